// Round 5
// baseline (833.677 us; speedup 1.0000x reference)
//
#include <hip/hip_runtime.h>
#include <stdint.h>

static constexpr int B  = 32;
static constexpr int T  = 350;
static constexpr int NIN = 2048;
static constexpr int NH  = 512;
static constexpr int NO  = 10;
static constexpr int BT  = B * T;

static constexpr float THETA = 10.0f;
static constexpr float BETA  = 0.36787944117144233f;   // e^-1 (refractory decay)
static constexpr float CREF  = 54.365636569180904707f; // SCALE_REF*THETA*e = 20e

// Workspace layout (bytes). Peak 50.07 MB.
static constexpr size_t OFF_W1T   = 0;                  // 2048*512 f32 = 4,194,304
static constexpr size_t OFF_SRM   = 4194304;            // 192 f32 (1 KB slot)
static constexpr size_t OFF_Z1    = 4195328;            // BT*512 f32 = 22,937,600
static constexpr size_t OFF_A1    = 27132928;           // BT*512 f32 -> ends 50,070,528
static constexpr size_t OFF_MASKT = OFF_A1;             // 32*6*2048 u64 = 3,145,728 (dead before a1 written)
static constexpr size_t OFF_Z2    = OFF_A1;             // BT*10 f32 (a1+maskt dead)

// ============ k_prep: pack (blocks 0..1023) + W1 transpose (1024..2047) + srm (2048)
// maskt[(b*6+c)*2048 + n] = u64 of t-bits for t = c*64 + bit  (bits t>=T are 0)
__global__ void __launch_bounds__(256) k_prep(const float* __restrict__ x,
                                              const float* __restrict__ W1,
                                              float* __restrict__ W1T,
                                              uint64_t* __restrict__ maskt,
                                              float* __restrict__ srm28) {
    int bid = blockIdx.x;
    if (bid < 1024) {
        __shared__ uint64_t tb[6][64];
        int b = bid >> 5, nblk = bid & 31;
        int wv = threadIdx.x >> 6, lane = threadIdx.x & 63;
        for (int nr = wv; nr < 64; nr += 4) {
            const float* xp = x + ((size_t)b * NIN + nblk * 64 + nr) * T;
            #pragma unroll
            for (int c = 0; c < 6; ++c) {
                int t = c * 64 + lane;
                float v = (t < T) ? xp[t] : 0.f;
                uint64_t mk = __ballot(v != 0.0f);
                if (lane == 0) tb[c][nr] = mk;
            }
        }
        __syncthreads();
        for (int i = threadIdx.x; i < 6 * 64; i += 256) {
            int c = i >> 6, nr = i & 63;
            maskt[((size_t)b * 6 + c) * 2048 + nblk * 64 + nr] = tb[c][nr];
        }
    } else if (bid < 2048) {
        __shared__ float tile[32][33];
        int idx = bid - 1024;
        int n0 = (idx & 63) * 32, m0 = (idx >> 6) * 32;
        int tx = threadIdx.x & 31, ty0 = threadIdx.x >> 5;
        #pragma unroll
        for (int i = 0; i < 4; ++i) {
            int ty = ty0 + 8 * i;
            tile[ty][tx] = W1[(size_t)(m0 + ty) * NIN + n0 + tx];
        }
        __syncthreads();
        #pragma unroll
        for (int i = 0; i < 4; ++i) {
            int ty = ty0 + 8 * i;
            W1T[(size_t)(n0 + ty) * NH + m0 + tx] = tile[tx][ty];
        }
    } else {
        int j = threadIdx.x;
        if (j < 192) {
            float v = 0.f;
            int i = j - 28;
            if (i >= 0 && i < 100) { float t = (float)i; v = (t * 0.1f) * expf(1.f - t * 0.1f); }
            srm28[j] = v;
        }
    }
}

// ============ k_z1 v3: row-tiled sparse accumulate.
// block = (b, c = t-chunk of 64, mq = m-quarter of 128); 4 waves x (16 rows x 128 m).
// Per n: wave-uniform 16-bit row field -> scalar skip; batched guarded loads (MLP);
// ctz/switch dispatch into 16x float2 register accumulators. Ascending-n order.
__global__ void __launch_bounds__(256) k_z1(const uint64_t* __restrict__ maskt,
                                            const float* __restrict__ W1T,
                                            float* __restrict__ z1) {
    __shared__ uint64_t sm[2048];
    int blk = blockIdx.x;                  // 768 = 32 b * 6 c * 4 mq
    int mq = blk & 3;
    int c  = (blk >> 2) % 6;
    int b  = blk / 24;
    int wv = threadIdx.x >> 6, lane = threadIdx.x & 63;
    const uint64_t* mp = maskt + ((size_t)b * 6 + c) * 2048;
    for (int i = threadIdx.x; i < 2048; i += 256) sm[i] = mp[i];
    __syncthreads();

    int sh = wv * 16;
    int t0 = c * 64 + sh;
    if (t0 >= T) return;                   // dead waves (last chunk) exit after fill
    int m0 = mq * 128 + lane * 2;
    const float* Wp = W1T + m0;

    float2 acc[16];
    #pragma unroll
    for (int r = 0; r < 16; ++r) acc[r] = make_float2(0.f, 0.f);

    for (int n8 = 0; n8 < 2048; n8 += 8) {
        uint32_t f[8];
        #pragma unroll
        for (int j = 0; j < 8; ++j)
            f[j] = (uint32_t)((sm[n8 + j] >> sh) & 0xFFFFu);
        float2 w[8];
        #pragma unroll
        for (int j = 0; j < 8; ++j)
            if (f[j]) w[j] = *(const float2*)(Wp + (size_t)(n8 + j) * NH);
        #pragma unroll
        for (int j = 0; j < 8; ++j) {
            uint32_t fj = f[j];
            if (!fj) continue;
            float2 wj = w[j];
            while (fj) {
                int r = __builtin_ctz(fj);
                fj &= fj - 1;
                switch (r) {
                    case 0:  acc[0].x  += wj.x; acc[0].y  += wj.y; break;
                    case 1:  acc[1].x  += wj.x; acc[1].y  += wj.y; break;
                    case 2:  acc[2].x  += wj.x; acc[2].y  += wj.y; break;
                    case 3:  acc[3].x  += wj.x; acc[3].y  += wj.y; break;
                    case 4:  acc[4].x  += wj.x; acc[4].y  += wj.y; break;
                    case 5:  acc[5].x  += wj.x; acc[5].y  += wj.y; break;
                    case 6:  acc[6].x  += wj.x; acc[6].y  += wj.y; break;
                    case 7:  acc[7].x  += wj.x; acc[7].y  += wj.y; break;
                    case 8:  acc[8].x  += wj.x; acc[8].y  += wj.y; break;
                    case 9:  acc[9].x  += wj.x; acc[9].y  += wj.y; break;
                    case 10: acc[10].x += wj.x; acc[10].y += wj.y; break;
                    case 11: acc[11].x += wj.x; acc[11].y += wj.y; break;
                    case 12: acc[12].x += wj.x; acc[12].y += wj.y; break;
                    case 13: acc[13].x += wj.x; acc[13].y += wj.y; break;
                    case 14: acc[14].x += wj.x; acc[14].y += wj.y; break;
                    default: acc[15].x += wj.x; acc[15].y += wj.y; break;
                }
            }
        }
    }
    #pragma unroll
    for (int r = 0; r < 16; ++r) {
        int t = t0 + r;
        if (t < T) *(float2*)(z1 + ((size_t)b * T + t) * NH + m0) = acc[r];
    }
}

// ============ k_fir1: causal FIR K=100, M=512 (unchanged from R4)
__global__ void __launch_bounds__(64) k_fir1(const float* __restrict__ src,
                                             float* __restrict__ dst,
                                             const float* __restrict__ srm28) {
    __shared__ float tb[192];
    int b = blockIdx.x, half = blockIdx.y, tg = blockIdx.z;
    int lane = threadIdx.x;
    for (int i = lane; i < 192; i += 64) tb[i] = srm28[i];
    __syncthreads();
    int t0 = tg * 16;
    int m = half * 256 + lane * 4;
    const float* sp = src + (size_t)b * T * NH + m;

    float4 acc[16];
    #pragma unroll
    for (int r = 0; r < 16; ++r) acc[r] = make_float4(0.f, 0.f, 0.f, 0.f);
    float c[16];
    #pragma unroll
    for (int r = 0; r < 16; ++r) c[r] = tb[r + 127];

    for (int o = 0; o < 8; ++o) {
        #pragma unroll
        for (int j = 0; j < 16; ++j) {
            int dd = o * 16 + j;
            int tau = t0 - 99 + dd;
            float4 v = make_float4(0.f, 0.f, 0.f, 0.f);
            if (tau >= 0 && tau < T) v = *(const float4*)(sp + (size_t)tau * NH);
            #pragma unroll
            for (int r = 0; r < 16; ++r) {
                acc[r].x += c[r] * v.x; acc[r].y += c[r] * v.y;
                acc[r].z += c[r] * v.z; acc[r].w += c[r] * v.w;
            }
            #pragma unroll
            for (int r = 15; r > 0; --r) c[r] = c[r - 1];
            int ci = 126 - dd;
            c[0] = tb[ci < 0 ? 0 : ci];
        }
    }
    #pragma unroll
    for (int r = 0; r < 16; ++r) {
        int t = t0 + r;
        if (t < T) *(float4*)(dst + ((size_t)b * T + t) * NH + m) = acc[r];
    }
}

// ============ scan layer 1 (unchanged)
template<int M, int LAYOUT_TM>
__global__ void k_scan_t(const float* __restrict__ u, float* __restrict__ s) {
    constexpr int CT = 16;
    constexpr int NC = (T + CT - 1) / CT;
    int tid = blockIdx.x * blockDim.x + threadIdx.x;
    if (tid >= B * M) return;
    int b = tid / M, m = tid - b * M;
    const float* up = u + (size_t)b * T * M + m;
    float cur[CT], nxt[CT];
    float A = 0.f, Bs = 0.f;
    #pragma unroll
    for (int j = 0; j < CT; ++j) cur[j] = up[(size_t)j * M];
    for (int c = 0; c < NC; ++c) {
        int t0 = c * CT;
        int nsteps = (T - t0 < CT) ? (T - t0) : CT;
        if (c + 1 < NC) {
            int t1 = t0 + CT;
            #pragma unroll
            for (int j = 0; j < CT; ++j) {
                int t = t1 + j;
                nxt[j] = (t < T) ? up[(size_t)t * M] : 0.f;
            }
        }
        float outbuf[CT];
        #pragma unroll
        for (int j = 0; j < CT; ++j) {
            if (j < nsteps) {
                float mem = cur[j] - CREF * Bs;
                float sp = (mem >= THETA) ? 1.0f : 0.0f;
                A = sp + BETA * A;
                Bs = BETA * (Bs + A);
                if (LAYOUT_TM) s[((size_t)b * T + (t0 + j)) * M + m] = sp;
                else           outbuf[j] = sp;
            }
        }
        if (!LAYOUT_TM) {
            #pragma unroll
            for (int j = 0; j < CT; ++j)
                if (j < nsteps) s[((size_t)(b * M + m)) * T + t0 + j] = outbuf[j];
        }
        #pragma unroll
        for (int j = 0; j < CT; ++j) cur[j] = nxt[j];
    }
}

// ============ k_z2 (unchanged)
__global__ void __launch_bounds__(64) k_z2(const float* __restrict__ s1,
                                           const float* __restrict__ W2,
                                           float* __restrict__ z2) {
    int row = blockIdx.x;
    int lane = threadIdx.x;
    const float* sp = s1 + (size_t)row * NH;
    float acc[NO];
    #pragma unroll
    for (int o = 0; o < NO; ++o) acc[o] = 0.f;
    for (int j = 0; j < 8; ++j) {
        int m = lane + 64 * j;
        float sv = sp[m];
        #pragma unroll
        for (int o = 0; o < NO; ++o) acc[o] += sv * W2[(size_t)o * NH + m];
    }
    #pragma unroll
    for (int o = 0; o < NO; ++o) {
        float v = acc[o];
        for (int off = 32; off > 0; off >>= 1) v += __shfl_down(v, off);
        if (lane == 0) z2[(size_t)row * NO + o] = v;
    }
}

// ============ k_fir2scan (unchanged)
__global__ void __launch_bounds__(256) k_fir2scan(const float* __restrict__ z2,
                                                  const float* __restrict__ srm28,
                                                  float* __restrict__ out) {
    __shared__ float tb[192];
    __shared__ float zb[350 * 11 + 16];
    __shared__ float ab[352 * 10];
    int b = blockIdx.x, tid = threadIdx.x;
    if (tid < 192) tb[tid] = srm28[tid];
    const float* zp = z2 + (size_t)b * T * NO;
    for (int i = tid; i < T * NO; i += 256) {
        int t = i / NO, o = i - t * NO;
        zb[t * 11 + o] = zp[i];
    }
    __syncthreads();
    if (tid < 220) {
        int tt = tid / 10, o = tid - tt * 10;
        int t0 = tt * 16;
        float acc[16];
        #pragma unroll
        for (int r = 0; r < 16; ++r) acc[r] = 0.f;
        float c[16];
        #pragma unroll
        for (int r = 0; r < 16; ++r) c[r] = tb[r + 127];
        for (int oo = 0; oo < 8; ++oo) {
            #pragma unroll
            for (int j = 0; j < 16; ++j) {
                int dd = oo * 16 + j;
                int tau = t0 - 99 + dd;
                float v = (tau >= 0 && tau < T) ? zb[tau * 11 + o] : 0.f;
                #pragma unroll
                for (int r = 0; r < 16; ++r) acc[r] += c[r] * v;
                #pragma unroll
                for (int r = 15; r > 0; --r) c[r] = c[r - 1];
                int ci = 126 - dd;
                c[0] = tb[ci < 0 ? 0 : ci];
            }
        }
        #pragma unroll
        for (int r = 0; r < 16; ++r) {
            int t = t0 + r;
            if (t < T) ab[t * 10 + o] = acc[r];
        }
    }
    __syncthreads();
    if (tid < NO) {
        int o = tid;
        float A = 0.f, Bs = 0.f;
        float* op = out + ((size_t)b * NO + o) * T;
        for (int t = 0; t < T; ++t) {
            float mem = ab[t * 10 + o] - CREF * Bs;
            float sp = (mem >= THETA) ? 1.0f : 0.0f;
            A = sp + BETA * A;
            Bs = BETA * (Bs + A);
            op[t] = sp;
        }
    }
}

extern "C" void kernel_launch(void* const* d_in, const int* in_sizes, int n_in,
                              void* d_out, int out_size, void* d_ws, size_t ws_size,
                              hipStream_t stream) {
    const float* x  = (const float*)d_in[0];
    const float* W1 = (const float*)d_in[1];
    const float* W2 = (const float*)d_in[2];
    char* ws = (char*)d_ws;
    float*    W1T   = (float*)(ws + OFF_W1T);
    float*    srm   = (float*)(ws + OFF_SRM);
    float*    z1    = (float*)(ws + OFF_Z1);
    float*    a1    = (float*)(ws + OFF_A1);
    uint64_t* maskt = (uint64_t*)(ws + OFF_MASKT);
    float*    s1    = z1;                      // reuse: z1 dead after fir1
    float*    z2    = (float*)(ws + OFF_Z2);   // reuse: a1 + maskt dead
    float*    out   = (float*)d_out;

    hipLaunchKernelGGL(k_prep,            dim3(2049),       dim3(256), 0, stream, x, W1, W1T, maskt, srm);
    hipLaunchKernelGGL(k_z1,              dim3(768),        dim3(256), 0, stream, maskt, W1T, z1);
    hipLaunchKernelGGL(k_fir1,            dim3(B, 2, 22),   dim3(64),  0, stream, z1, a1, srm);
    hipLaunchKernelGGL((k_scan_t<NH, 1>), dim3((B*NH)/64),  dim3(64),  0, stream, a1, s1);
    hipLaunchKernelGGL(k_z2,              dim3(BT),         dim3(64),  0, stream, s1, W2, z2);
    hipLaunchKernelGGL(k_fir2scan,        dim3(B),          dim3(256), 0, stream, z2, srm, out);
}

// Round 6
// 570.164 us; speedup vs baseline: 1.4622x; 1.4622x over previous
//
#include <hip/hip_runtime.h>
#include <stdint.h>

static constexpr int B  = 32;
static constexpr int T  = 350;
static constexpr int NIN = 2048;
static constexpr int NH  = 512;
static constexpr int NO  = 10;
static constexpr int BT  = B * T;

static constexpr float THETA = 10.0f;
static constexpr float BETA  = 0.36787944117144233f;   // e^-1 (refractory decay)
static constexpr float CREF  = 54.365636569180904707f; // SCALE_REF*THETA*e = 20e

// Workspace layout (bytes). Peak 50.07 MB.
static constexpr size_t OFF_W1T   = 0;                  // 2048*512 f32 = 4,194,304
static constexpr size_t OFF_SRM   = 4194304;            // 192 f32 (1 KB slot)
static constexpr size_t OFF_Z1    = 4195328;            // BT*512 f32 = 22,937,600
static constexpr size_t OFF_A1    = 27132928;           // BT*512 f32 -> ends 50,070,528
static constexpr size_t OFF_MASKT = OFF_A1;             // 32*6*2048 u64 (dead before a1 written)
static constexpr size_t OFF_Z2    = OFF_A1;             // BT*10 f32 (a1+maskt dead)

// ============ k_prep: pack (0..1023) + W1 transpose (1024..2047) + srm (2048)
// maskt[(b*6+c)*2048 + n] = u64 of t-bits for t = c*64 + bit  (bits t>=T are 0)
__global__ void __launch_bounds__(256) k_prep(const float* __restrict__ x,
                                              const float* __restrict__ W1,
                                              float* __restrict__ W1T,
                                              uint64_t* __restrict__ maskt,
                                              float* __restrict__ srm28) {
    int bid = blockIdx.x;
    if (bid < 1024) {
        __shared__ uint64_t tb[6][64];
        int b = bid >> 5, nblk = bid & 31;
        int wv = threadIdx.x >> 6, lane = threadIdx.x & 63;
        for (int nr = wv; nr < 64; nr += 4) {
            const float* xp = x + ((size_t)b * NIN + nblk * 64 + nr) * T;
            #pragma unroll
            for (int c = 0; c < 6; ++c) {
                int t = c * 64 + lane;
                float v = (t < T) ? xp[t] : 0.f;
                uint64_t mk = __ballot(v != 0.0f);
                if (lane == 0) tb[c][nr] = mk;
            }
        }
        __syncthreads();
        for (int i = threadIdx.x; i < 6 * 64; i += 256) {
            int c = i >> 6, nr = i & 63;
            maskt[((size_t)b * 6 + c) * 2048 + nblk * 64 + nr] = tb[c][nr];
        }
    } else if (bid < 2048) {
        __shared__ float tile[32][33];
        int idx = bid - 1024;
        int n0 = (idx & 63) * 32, m0 = (idx >> 6) * 32;
        int tx = threadIdx.x & 31, ty0 = threadIdx.x >> 5;
        #pragma unroll
        for (int i = 0; i < 4; ++i) {
            int ty = ty0 + 8 * i;
            tile[ty][tx] = W1[(size_t)(m0 + ty) * NIN + n0 + tx];
        }
        __syncthreads();
        #pragma unroll
        for (int i = 0; i < 4; ++i) {
            int ty = ty0 + 8 * i;
            W1T[(size_t)(n0 + ty) * NH + m0 + tx] = tile[tx][ty];
        }
    } else {
        int j = threadIdx.x;
        if (j < 192) {
            float v = 0.f;
            int i = j - 28;
            if (i >= 0 && i < 100) { float t = (float)i; v = (t * 0.1f) * expf(1.f - t * 0.1f); }
            srm28[j] = v;
        }
    }
}

// ============ k_z1 v4: one wave per (b, c, 16-t subtile), all 512 m (float8/lane).
// Uniform s_load mask words, uniform scalar skip; accumulate via branch-free
// bitf*w FMA with nibble-level uniform skip. Constant acc indices, no switch.
// Ascending-n summation order (bit-exact vs R3/R4).
__global__ void __launch_bounds__(64) k_z1(const uint64_t* __restrict__ maskt,
                                           const float* __restrict__ W1T,
                                           float* __restrict__ z1) {
    int blk = blockIdx.x;                 // ((b*6+c)<<2) | wv
    int wv = blk & 3;
    int bc = blk >> 2;                    // b*6 + c
    int c  = bc % 6;
    int b  = bc / 6;
    int t0 = c * 64 + wv * 16;
    if (t0 >= T) return;
    int sh = wv * 16;
    int lane = threadIdx.x;
    const uint64_t* mp = maskt + (size_t)bc * 2048;
    const float* Wb = W1T + lane * 8;

    float4 accA[16], accB[16];
    #pragma unroll
    for (int r = 0; r < 16; ++r) {
        accA[r] = make_float4(0.f, 0.f, 0.f, 0.f);
        accB[r] = make_float4(0.f, 0.f, 0.f, 0.f);
    }

    for (int n4 = 0; n4 < 2048; n4 += 4) {
        uint32_t f[4];
        #pragma unroll
        for (int j = 0; j < 4; ++j)
            f[j] = (uint32_t)((mp[n4 + j] >> sh) & 0xFFFFu);  // uniform -> s_load/s_lshr
        float4 wa[4], wb[4];
        #pragma unroll
        for (int j = 0; j < 4; ++j)
            if (f[j]) {
                const float* rp = Wb + (size_t)(n4 + j) * NH;
                wa[j] = *(const float4*)rp;
                wb[j] = *(const float4*)(rp + 4);
            }
        #pragma unroll
        for (int j = 0; j < 4; ++j) {
            uint32_t fj = f[j];
            if (!fj) continue;                       // uniform skip
            float4 va = wa[j], vb = wb[j];
            #pragma unroll
            for (int q = 0; q < 4; ++q) {            // nibble-level uniform skip
                if (fj & (0xFu << (4 * q))) {
                    #pragma unroll
                    for (int ri = 0; ri < 4; ++ri) {
                        int r = 4 * q + ri;
                        float bf = (float)((fj >> r) & 1u);  // branch-free 0/1
                        accA[r].x += bf * va.x; accA[r].y += bf * va.y;
                        accA[r].z += bf * va.z; accA[r].w += bf * va.w;
                        accB[r].x += bf * vb.x; accB[r].y += bf * vb.y;
                        accB[r].z += bf * vb.z; accB[r].w += bf * vb.w;
                    }
                }
            }
        }
    }
    #pragma unroll
    for (int r = 0; r < 16; ++r) {
        int t = t0 + r;
        if (t < T) {
            float* zp = z1 + ((size_t)b * T + t) * NH + lane * 8;
            *(float4*)zp = accA[r];
            *(float4*)(zp + 4) = accB[r];
        }
    }
}

// ============ k_fir1: causal FIR K=100, M=512 (unchanged)
__global__ void __launch_bounds__(64) k_fir1(const float* __restrict__ src,
                                             float* __restrict__ dst,
                                             const float* __restrict__ srm28) {
    __shared__ float tb[192];
    int b = blockIdx.x, half = blockIdx.y, tg = blockIdx.z;
    int lane = threadIdx.x;
    for (int i = lane; i < 192; i += 64) tb[i] = srm28[i];
    __syncthreads();
    int t0 = tg * 16;
    int m = half * 256 + lane * 4;
    const float* sp = src + (size_t)b * T * NH + m;

    float4 acc[16];
    #pragma unroll
    for (int r = 0; r < 16; ++r) acc[r] = make_float4(0.f, 0.f, 0.f, 0.f);
    float c[16];
    #pragma unroll
    for (int r = 0; r < 16; ++r) c[r] = tb[r + 127];

    for (int o = 0; o < 8; ++o) {
        #pragma unroll
        for (int j = 0; j < 16; ++j) {
            int dd = o * 16 + j;
            int tau = t0 - 99 + dd;
            float4 v = make_float4(0.f, 0.f, 0.f, 0.f);
            if (tau >= 0 && tau < T) v = *(const float4*)(sp + (size_t)tau * NH);
            #pragma unroll
            for (int r = 0; r < 16; ++r) {
                acc[r].x += c[r] * v.x; acc[r].y += c[r] * v.y;
                acc[r].z += c[r] * v.z; acc[r].w += c[r] * v.w;
            }
            #pragma unroll
            for (int r = 15; r > 0; --r) c[r] = c[r - 1];
            int ci = 126 - dd;
            c[0] = tb[ci < 0 ? 0 : ci];
        }
    }
    #pragma unroll
    for (int r = 0; r < 16; ++r) {
        int t = t0 + r;
        if (t < T) *(float4*)(dst + ((size_t)b * T + t) * NH + m) = acc[r];
    }
}

// ============ scan layer 1 (unchanged)
template<int M, int LAYOUT_TM>
__global__ void k_scan_t(const float* __restrict__ u, float* __restrict__ s) {
    constexpr int CT = 16;
    constexpr int NC = (T + CT - 1) / CT;
    int tid = blockIdx.x * blockDim.x + threadIdx.x;
    if (tid >= B * M) return;
    int b = tid / M, m = tid - b * M;
    const float* up = u + (size_t)b * T * M + m;
    float cur[CT], nxt[CT];
    float A = 0.f, Bs = 0.f;
    #pragma unroll
    for (int j = 0; j < CT; ++j) cur[j] = up[(size_t)j * M];
    for (int c = 0; c < NC; ++c) {
        int t0 = c * CT;
        int nsteps = (T - t0 < CT) ? (T - t0) : CT;
        if (c + 1 < NC) {
            int t1 = t0 + CT;
            #pragma unroll
            for (int j = 0; j < CT; ++j) {
                int t = t1 + j;
                nxt[j] = (t < T) ? up[(size_t)t * M] : 0.f;
            }
        }
        float outbuf[CT];
        #pragma unroll
        for (int j = 0; j < CT; ++j) {
            if (j < nsteps) {
                float mem = cur[j] - CREF * Bs;
                float sp = (mem >= THETA) ? 1.0f : 0.0f;
                A = sp + BETA * A;
                Bs = BETA * (Bs + A);
                if (LAYOUT_TM) s[((size_t)b * T + (t0 + j)) * M + m] = sp;
                else           outbuf[j] = sp;
            }
        }
        if (!LAYOUT_TM) {
            #pragma unroll
            for (int j = 0; j < CT; ++j)
                if (j < nsteps) s[((size_t)(b * M + m)) * T + t0 + j] = outbuf[j];
        }
        #pragma unroll
        for (int j = 0; j < CT; ++j) cur[j] = nxt[j];
    }
}

// ============ k_z2 (unchanged)
__global__ void __launch_bounds__(64) k_z2(const float* __restrict__ s1,
                                           const float* __restrict__ W2,
                                           float* __restrict__ z2) {
    int row = blockIdx.x;
    int lane = threadIdx.x;
    const float* sp = s1 + (size_t)row * NH;
    float acc[NO];
    #pragma unroll
    for (int o = 0; o < NO; ++o) acc[o] = 0.f;
    for (int j = 0; j < 8; ++j) {
        int m = lane + 64 * j;
        float sv = sp[m];
        #pragma unroll
        for (int o = 0; o < NO; ++o) acc[o] += sv * W2[(size_t)o * NH + m];
    }
    #pragma unroll
    for (int o = 0; o < NO; ++o) {
        float v = acc[o];
        for (int off = 32; off > 0; off >>= 1) v += __shfl_down(v, off);
        if (lane == 0) z2[(size_t)row * NO + o] = v;
    }
}

// ============ k_fir2scan (unchanged)
__global__ void __launch_bounds__(256) k_fir2scan(const float* __restrict__ z2,
                                                  const float* __restrict__ srm28,
                                                  float* __restrict__ out) {
    __shared__ float tb[192];
    __shared__ float zb[350 * 11 + 16];
    __shared__ float ab[352 * 10];
    int b = blockIdx.x, tid = threadIdx.x;
    if (tid < 192) tb[tid] = srm28[tid];
    const float* zp = z2 + (size_t)b * T * NO;
    for (int i = tid; i < T * NO; i += 256) {
        int t = i / NO, o = i - t * NO;
        zb[t * 11 + o] = zp[i];
    }
    __syncthreads();
    if (tid < 220) {
        int tt = tid / 10, o = tid - tt * 10;
        int t0 = tt * 16;
        float acc[16];
        #pragma unroll
        for (int r = 0; r < 16; ++r) acc[r] = 0.f;
        float c[16];
        #pragma unroll
        for (int r = 0; r < 16; ++r) c[r] = tb[r + 127];
        for (int oo = 0; oo < 8; ++oo) {
            #pragma unroll
            for (int j = 0; j < 16; ++j) {
                int dd = oo * 16 + j;
                int tau = t0 - 99 + dd;
                float v = (tau >= 0 && tau < T) ? zb[tau * 11 + o] : 0.f;
                #pragma unroll
                for (int r = 0; r < 16; ++r) acc[r] += c[r] * v;
                #pragma unroll
                for (int r = 15; r > 0; --r) c[r] = c[r - 1];
                int ci = 126 - dd;
                c[0] = tb[ci < 0 ? 0 : ci];
            }
        }
        #pragma unroll
        for (int r = 0; r < 16; ++r) {
            int t = t0 + r;
            if (t < T) ab[t * 10 + o] = acc[r];
        }
    }
    __syncthreads();
    if (tid < NO) {
        int o = tid;
        float A = 0.f, Bs = 0.f;
        float* op = out + ((size_t)b * NO + o) * T;
        for (int t = 0; t < T; ++t) {
            float mem = ab[t * 10 + o] - CREF * Bs;
            float sp = (mem >= THETA) ? 1.0f : 0.0f;
            A = sp + BETA * A;
            Bs = BETA * (Bs + A);
            op[t] = sp;
        }
    }
}

extern "C" void kernel_launch(void* const* d_in, const int* in_sizes, int n_in,
                              void* d_out, int out_size, void* d_ws, size_t ws_size,
                              hipStream_t stream) {
    const float* x  = (const float*)d_in[0];
    const float* W1 = (const float*)d_in[1];
    const float* W2 = (const float*)d_in[2];
    char* ws = (char*)d_ws;
    float*    W1T   = (float*)(ws + OFF_W1T);
    float*    srm   = (float*)(ws + OFF_SRM);
    float*    z1    = (float*)(ws + OFF_Z1);
    float*    a1    = (float*)(ws + OFF_A1);
    uint64_t* maskt = (uint64_t*)(ws + OFF_MASKT);
    float*    s1    = z1;                      // reuse: z1 dead after fir1
    float*    z2    = (float*)(ws + OFF_Z2);   // reuse: a1 + maskt dead
    float*    out   = (float*)d_out;

    hipLaunchKernelGGL(k_prep,            dim3(2049),       dim3(256), 0, stream, x, W1, W1T, maskt, srm);
    hipLaunchKernelGGL(k_z1,              dim3(768),        dim3(64),  0, stream, maskt, W1T, z1);
    hipLaunchKernelGGL(k_fir1,            dim3(B, 2, 22),   dim3(64),  0, stream, z1, a1, srm);
    hipLaunchKernelGGL((k_scan_t<NH, 1>), dim3((B*NH)/64),  dim3(64),  0, stream, a1, s1);
    hipLaunchKernelGGL(k_z2,              dim3(BT),         dim3(64),  0, stream, s1, W2, z2);
    hipLaunchKernelGGL(k_fir2scan,        dim3(B),          dim3(256), 0, stream, z2, srm, out);
}

// Round 7
// 423.072 us; speedup vs baseline: 1.9705x; 1.3477x over previous
//
#include <hip/hip_runtime.h>
#include <stdint.h>

static constexpr int B  = 32;
static constexpr int T  = 350;
static constexpr int NIN = 2048;
static constexpr int NH  = 512;
static constexpr int NO  = 10;
static constexpr int BT  = B * T;

static constexpr float THETA = 10.0f;
static constexpr float BETA  = 0.36787944117144233f;   // e^-1 (refractory decay)
static constexpr float CREF  = 54.365636569180904707f; // SCALE_REF*THETA*e = 20e

// Workspace layout (bytes). Peak ~52.94 MB.
static constexpr size_t OFF_W1T  = 0;                   // 2049*512 f32 (row 2048 = zeros)
static constexpr size_t OFF_MASK = 4196352;             // BT*32 u64 = 2,867,200
static constexpr size_t OFF_SRM  = 7063552;             // 192 f32 (offset-28 table)
static constexpr size_t OFF_Z1   = 7064576;             // BT*512 f32 = 22,937,600
static constexpr size_t OFF_A1   = 30002176;            // BT*512 f32
static constexpr size_t OFF_Z2   = OFF_A1;              // reuse (a1 dead when z2 written)

// ============ k_prep: pack (0..1023) + W1 transpose (1024..2047) + tables (2048)
__global__ void __launch_bounds__(256) k_prep(const float* __restrict__ x,
                                              const float* __restrict__ W1,
                                              float* __restrict__ W1T,
                                              uint64_t* __restrict__ mask,
                                              float* __restrict__ srm28) {
    int bid = blockIdx.x;
    if (bid < 1024) {
        // pack x [B][NIN][T] -> mask[b][t][nblk] (n-bit words) via coalesced reads
        // + 64x64 in-register bit transpose
        __shared__ uint64_t tb[6][64];
        int b = bid >> 5, nblk = bid & 31;
        int wv = threadIdx.x >> 6, lane = threadIdx.x & 63;
        for (int nr = wv; nr < 64; nr += 4) {
            const float* xp = x + ((size_t)b * NIN + nblk * 64 + nr) * T;
            #pragma unroll
            for (int c = 0; c < 6; ++c) {
                int t = c * 64 + lane;
                float v = (t < T) ? xp[t] : 0.f;
                uint64_t mk = __ballot(v != 0.0f);
                if (lane == 0) tb[c][nr] = mk;
            }
        }
        __syncthreads();
        static const uint64_t AM[6] = {
            0x00000000FFFFFFFFull, 0x0000FFFF0000FFFFull, 0x00FF00FF00FF00FFull,
            0x0F0F0F0F0F0F0F0Full, 0x3333333333333333ull, 0x5555555555555555ull };
        for (int c = wv; c < 6; c += 4) {
            uint64_t w = tb[c][lane];            // lane = n, bits = t
            #pragma unroll
            for (int i = 0; i < 6; ++i) {
                int s = 32 >> i;
                uint64_t A = AM[i];
                uint64_t y = __shfl_xor((unsigned long long)w, s);
                if ((lane & s) == 0) w = (w & A)  | ((y & A) << s);
                else                 w = (w & ~A) | ((y & ~A) >> s);
            }
            int t = c * 64 + lane;               // lane = t, bits = n
            if (t < T) mask[((size_t)b * T + t) * 32 + nblk] = w;
        }
    } else if (bid < 2048) {
        __shared__ float tile[32][33];
        int idx = bid - 1024;
        int n0 = (idx & 63) * 32, m0 = (idx >> 6) * 32;
        int tx = threadIdx.x & 31, ty0 = threadIdx.x >> 5;
        #pragma unroll
        for (int i = 0; i < 4; ++i) {
            int ty = ty0 + 8 * i;
            tile[ty][tx] = W1[(size_t)(m0 + ty) * NIN + n0 + tx];
        }
        __syncthreads();
        #pragma unroll
        for (int i = 0; i < 4; ++i) {
            int ty = ty0 + 8 * i;
            W1T[(size_t)(n0 + ty) * NH + m0 + tx] = tile[tx][ty];
        }
    } else {
        int j = threadIdx.x;
        if (j < 192) {
            float v = 0.f;
            int i = j - 28;
            if (i >= 0 && i < 100) { float t = (float)i; v = (t * 0.1f) * expf(1.f - t * 0.1f); }
            srm28[j] = v;
        }
        for (int i = j; i < NH; i += 256) W1T[(size_t)2048 * NH + i] = 0.f;
    }
}

// ============ k_z1_half<H>: z1[b,t, H*256 .. H*256+255] = sum over active n of
// W1T[n, half]. One wave per (b,t); mask -> LDS index list (padded x8 with
// zero-row 2048); gather 8 rows per iteration (8 dwordx4 in flight).
// Ascending-n summation -> bit-identical to R4's full-width gather.
template<int H>
__global__ void __launch_bounds__(64) k_z1_half(const uint64_t* __restrict__ mask,
                                                const float* __restrict__ W1T,
                                                float* __restrict__ z1) {
    __shared__ alignas(8) uint16_t lst[320];
    int row = blockIdx.x, lane = threadIdx.x;
    const uint64_t* mrow = mask + (size_t)row * 32;
    uint64_t w = (lane < 32) ? mrow[lane] : 0ull;
    int cnt = __popcll(w);
    int pre = cnt;
    #pragma unroll
    for (int off = 1; off < 64; off <<= 1) {
        int v = __shfl_up(pre, off);
        if (lane >= off) pre += v;
    }
    int total = __shfl(pre, 63);
    int excl = pre - cnt;
    while (w) {
        int bit = __builtin_ctzll(w);
        w &= w - 1;
        lst[excl++] = (uint16_t)((lane << 6) + bit);
    }
    int padded = (total + 7) & ~7;
    if (lane < padded - total) lst[total + lane] = 2048;   // zero row
    __syncthreads();

    const float4* W4 = (const float4*)W1T;
    float4 acc = {0, 0, 0, 0};
    int idx = H * 64 + lane;                 // float4 index within row
    for (int k = 0; k < padded; k += 8) {
        ushort4 q0 = *(const ushort4*)(lst + k);
        ushort4 q1 = *(const ushort4*)(lst + k + 4);
        float4 x0 = W4[(size_t)q0.x * 128 + idx];
        float4 x1 = W4[(size_t)q0.y * 128 + idx];
        float4 x2 = W4[(size_t)q0.z * 128 + idx];
        float4 x3 = W4[(size_t)q0.w * 128 + idx];
        float4 x4 = W4[(size_t)q1.x * 128 + idx];
        float4 x5 = W4[(size_t)q1.y * 128 + idx];
        float4 x6 = W4[(size_t)q1.z * 128 + idx];
        float4 x7 = W4[(size_t)q1.w * 128 + idx];
        acc.x += x0.x; acc.y += x0.y; acc.z += x0.z; acc.w += x0.w;
        acc.x += x1.x; acc.y += x1.y; acc.z += x1.z; acc.w += x1.w;
        acc.x += x2.x; acc.y += x2.y; acc.z += x2.z; acc.w += x2.w;
        acc.x += x3.x; acc.y += x3.y; acc.z += x3.z; acc.w += x3.w;
        acc.x += x4.x; acc.y += x4.y; acc.z += x4.z; acc.w += x4.w;
        acc.x += x5.x; acc.y += x5.y; acc.z += x5.z; acc.w += x5.w;
        acc.x += x6.x; acc.y += x6.y; acc.z += x6.z; acc.w += x6.w;
        acc.x += x7.x; acc.y += x7.y; acc.z += x7.z; acc.w += x7.w;
    }
    ((float4*)(z1 + (size_t)row * NH))[idx] = acc;
}

// ============ k_fir1: causal FIR K=100, M=512 (R4-exact)
__global__ void __launch_bounds__(64) k_fir1(const float* __restrict__ src,
                                             float* __restrict__ dst,
                                             const float* __restrict__ srm28) {
    __shared__ float tb[192];
    int b = blockIdx.x, half = blockIdx.y, tg = blockIdx.z;
    int lane = threadIdx.x;
    for (int i = lane; i < 192; i += 64) tb[i] = srm28[i];
    __syncthreads();
    int t0 = tg * 16;
    int m = half * 256 + lane * 4;
    const float* sp = src + (size_t)b * T * NH + m;

    float4 acc[16];
    #pragma unroll
    for (int r = 0; r < 16; ++r) acc[r] = make_float4(0.f, 0.f, 0.f, 0.f);
    float c[16];
    #pragma unroll
    for (int r = 0; r < 16; ++r) c[r] = tb[r + 127];

    for (int o = 0; o < 8; ++o) {
        #pragma unroll
        for (int j = 0; j < 16; ++j) {
            int dd = o * 16 + j;
            int tau = t0 - 99 + dd;
            float4 v = make_float4(0.f, 0.f, 0.f, 0.f);
            if (tau >= 0 && tau < T) v = *(const float4*)(sp + (size_t)tau * NH);
            #pragma unroll
            for (int r = 0; r < 16; ++r) {
                acc[r].x += c[r] * v.x; acc[r].y += c[r] * v.y;
                acc[r].z += c[r] * v.z; acc[r].w += c[r] * v.w;
            }
            #pragma unroll
            for (int r = 15; r > 0; --r) c[r] = c[r - 1];
            int ci = 126 - dd;
            c[0] = tb[ci < 0 ? 0 : ci];
        }
    }
    #pragma unroll
    for (int r = 0; r < 16; ++r) {
        int t = t0 + r;
        if (t < T) *(float4*)(dst + ((size_t)b * T + t) * NH + m) = acc[r];
    }
}

// ============ scan layer 1 (R4-exact)
template<int M, int LAYOUT_TM>
__global__ void k_scan_t(const float* __restrict__ u, float* __restrict__ s) {
    constexpr int CT = 16;
    constexpr int NC = (T + CT - 1) / CT;
    int tid = blockIdx.x * blockDim.x + threadIdx.x;
    if (tid >= B * M) return;
    int b = tid / M, m = tid - b * M;
    const float* up = u + (size_t)b * T * M + m;
    float cur[CT], nxt[CT];
    float A = 0.f, Bs = 0.f;
    #pragma unroll
    for (int j = 0; j < CT; ++j) cur[j] = up[(size_t)j * M];
    for (int c = 0; c < NC; ++c) {
        int t0 = c * CT;
        int nsteps = (T - t0 < CT) ? (T - t0) : CT;
        if (c + 1 < NC) {
            int t1 = t0 + CT;
            #pragma unroll
            for (int j = 0; j < CT; ++j) {
                int t = t1 + j;
                nxt[j] = (t < T) ? up[(size_t)t * M] : 0.f;
            }
        }
        float outbuf[CT];
        #pragma unroll
        for (int j = 0; j < CT; ++j) {
            if (j < nsteps) {
                float mem = cur[j] - CREF * Bs;
                float sp = (mem >= THETA) ? 1.0f : 0.0f;
                A = sp + BETA * A;
                Bs = BETA * (Bs + A);
                if (LAYOUT_TM) s[((size_t)b * T + (t0 + j)) * M + m] = sp;
                else           outbuf[j] = sp;
            }
        }
        if (!LAYOUT_TM) {
            #pragma unroll
            for (int j = 0; j < CT; ++j)
                if (j < nsteps) s[((size_t)(b * M + m)) * T + t0 + j] = outbuf[j];
        }
        #pragma unroll
        for (int j = 0; j < CT; ++j) cur[j] = nxt[j];
    }
}

// ============ k_z2 (R4-exact)
__global__ void __launch_bounds__(64) k_z2(const float* __restrict__ s1,
                                           const float* __restrict__ W2,
                                           float* __restrict__ z2) {
    int row = blockIdx.x;
    int lane = threadIdx.x;
    const float* sp = s1 + (size_t)row * NH;
    float acc[NO];
    #pragma unroll
    for (int o = 0; o < NO; ++o) acc[o] = 0.f;
    for (int j = 0; j < 8; ++j) {
        int m = lane + 64 * j;
        float sv = sp[m];
        #pragma unroll
        for (int o = 0; o < NO; ++o) acc[o] += sv * W2[(size_t)o * NH + m];
    }
    #pragma unroll
    for (int o = 0; o < NO; ++o) {
        float v = acc[o];
        for (int off = 32; off > 0; off >>= 1) v += __shfl_down(v, off);
        if (lane == 0) z2[(size_t)row * NO + o] = v;
    }
}

// ============ k_fir2scan (R4-exact)
__global__ void __launch_bounds__(256) k_fir2scan(const float* __restrict__ z2,
                                                  const float* __restrict__ srm28,
                                                  float* __restrict__ out) {
    __shared__ float tb[192];
    __shared__ float zb[350 * 11 + 16];
    __shared__ float ab[352 * 10];
    int b = blockIdx.x, tid = threadIdx.x;
    if (tid < 192) tb[tid] = srm28[tid];
    const float* zp = z2 + (size_t)b * T * NO;
    for (int i = tid; i < T * NO; i += 256) {
        int t = i / NO, o = i - t * NO;
        zb[t * 11 + o] = zp[i];
    }
    __syncthreads();
    if (tid < 220) {
        int tt = tid / 10, o = tid - tt * 10;
        int t0 = tt * 16;
        float acc[16];
        #pragma unroll
        for (int r = 0; r < 16; ++r) acc[r] = 0.f;
        float c[16];
        #pragma unroll
        for (int r = 0; r < 16; ++r) c[r] = tb[r + 127];
        for (int oo = 0; oo < 8; ++oo) {
            #pragma unroll
            for (int j = 0; j < 16; ++j) {
                int dd = oo * 16 + j;
                int tau = t0 - 99 + dd;
                float v = (tau >= 0 && tau < T) ? zb[tau * 11 + o] : 0.f;
                #pragma unroll
                for (int r = 0; r < 16; ++r) acc[r] += c[r] * v;
                #pragma unroll
                for (int r = 15; r > 0; --r) c[r] = c[r - 1];
                int ci = 126 - dd;
                c[0] = tb[ci < 0 ? 0 : ci];
            }
        }
        #pragma unroll
        for (int r = 0; r < 16; ++r) {
            int t = t0 + r;
            if (t < T) ab[t * 10 + o] = acc[r];
        }
    }
    __syncthreads();
    if (tid < NO) {
        int o = tid;
        float A = 0.f, Bs = 0.f;
        float* op = out + ((size_t)b * NO + o) * T;
        for (int t = 0; t < T; ++t) {
            float mem = ab[t * 10 + o] - CREF * Bs;
            float sp = (mem >= THETA) ? 1.0f : 0.0f;
            A = sp + BETA * A;
            Bs = BETA * (Bs + A);
            op[t] = sp;
        }
    }
}

extern "C" void kernel_launch(void* const* d_in, const int* in_sizes, int n_in,
                              void* d_out, int out_size, void* d_ws, size_t ws_size,
                              hipStream_t stream) {
    const float* x  = (const float*)d_in[0];
    const float* W1 = (const float*)d_in[1];
    const float* W2 = (const float*)d_in[2];
    char* ws = (char*)d_ws;
    float*    W1T  = (float*)(ws + OFF_W1T);
    uint64_t* mask = (uint64_t*)(ws + OFF_MASK);
    float*    srm  = (float*)(ws + OFF_SRM);
    float*    z1   = (float*)(ws + OFF_Z1);
    float*    a1   = (float*)(ws + OFF_A1);
    float*    s1   = z1;                       // reuse: z1 dead after fir1
    float*    z2   = (float*)(ws + OFF_Z2);    // reuse: a1 dead after scan1
    float*    out  = (float*)d_out;

    hipLaunchKernelGGL(k_prep,            dim3(2049),       dim3(256), 0, stream, x, W1, W1T, mask, srm);
    hipLaunchKernelGGL((k_z1_half<0>),    dim3(BT),         dim3(64),  0, stream, mask, W1T, z1);
    hipLaunchKernelGGL((k_z1_half<1>),    dim3(BT),         dim3(64),  0, stream, mask, W1T, z1);
    hipLaunchKernelGGL(k_fir1,            dim3(B, 2, 22),   dim3(64),  0, stream, z1, a1, srm);
    hipLaunchKernelGGL((k_scan_t<NH, 1>), dim3((B*NH)/64),  dim3(64),  0, stream, a1, s1);
    hipLaunchKernelGGL(k_z2,              dim3(BT),         dim3(64),  0, stream, s1, W2, z2);
    hipLaunchKernelGGL(k_fir2scan,        dim3(B),          dim3(256), 0, stream, z2, srm, out);
}

// Round 8
// 323.234 us; speedup vs baseline: 2.5792x; 1.3089x over previous
//
#include <hip/hip_runtime.h>
#include <stdint.h>

static constexpr int B  = 32;
static constexpr int T  = 350;
static constexpr int NIN = 2048;
static constexpr int NH  = 512;
static constexpr int NO  = 10;
static constexpr int BT  = B * T;

static constexpr float THETA = 10.0f;
static constexpr float BETA  = 0.36787944117144233f;   // e^-1 (refractory decay)
static constexpr float CREF  = 54.365636569180904707f; // SCALE_REF*THETA*e = 20e

// Workspace layout (bytes). Peak ~52.94 MB.
static constexpr size_t OFF_W1T  = 0;                   // 2049*512 f32 (row 2048 = zeros)
static constexpr size_t OFF_MASK = 4196352;             // BT*32 u64 = 2,867,200
static constexpr size_t OFF_SRM  = 7063552;             // 192 f32 (offset-28 table)
static constexpr size_t OFF_Z1   = 7064576;             // BT*512 f32 = 22,937,600
static constexpr size_t OFF_A1   = 30002176;            // BT*512 f32
static constexpr size_t OFF_Z2   = OFF_Z1;              // reuse (z1 dead after fir1)

// ============ k_prep: pack (0..1023) + W1 transpose (1024..2047) + tables (2048)
__global__ void __launch_bounds__(256) k_prep(const float* __restrict__ x,
                                              const float* __restrict__ W1,
                                              float* __restrict__ W1T,
                                              uint64_t* __restrict__ mask,
                                              float* __restrict__ srm28) {
    int bid = blockIdx.x;
    if (bid < 1024) {
        // pack x [B][NIN][T] -> mask[b][t][nblk]. 24 loads batched in registers
        // BEFORE any ballot (ballot's v_cmp otherwise serializes loads).
        __shared__ uint64_t tb[6][64];
        int b = bid >> 5, nblk = bid & 31;
        int wv = threadIdx.x >> 6, lane = threadIdx.x & 63;
        for (int g = 0; g < 4; ++g) {
            float v[4][6];
            #pragma unroll
            for (int i = 0; i < 4; ++i) {
                int nr = wv + 4 * (4 * g + i);
                const float* xp = x + ((size_t)b * NIN + nblk * 64 + nr) * T;
                #pragma unroll
                for (int c = 0; c < 6; ++c) {
                    int t = c * 64 + lane;
                    v[i][c] = (t < T) ? xp[t] : 0.f;
                }
            }
            #pragma unroll
            for (int i = 0; i < 4; ++i) {
                int nr = wv + 4 * (4 * g + i);
                #pragma unroll
                for (int c = 0; c < 6; ++c) {
                    uint64_t mk = __ballot(v[i][c] != 0.0f);
                    if (lane == 0) tb[c][nr] = mk;
                }
            }
        }
        __syncthreads();
        static const uint64_t AM[6] = {
            0x00000000FFFFFFFFull, 0x0000FFFF0000FFFFull, 0x00FF00FF00FF00FFull,
            0x0F0F0F0F0F0F0F0Full, 0x3333333333333333ull, 0x5555555555555555ull };
        for (int c = wv; c < 6; c += 4) {
            uint64_t w = tb[c][lane];            // lane = n, bits = t
            #pragma unroll
            for (int i = 0; i < 6; ++i) {
                int s = 32 >> i;
                uint64_t A = AM[i];
                uint64_t y = __shfl_xor((unsigned long long)w, s);
                if ((lane & s) == 0) w = (w & A)  | ((y & A) << s);
                else                 w = (w & ~A) | ((y & ~A) >> s);
            }
            int t = c * 64 + lane;               // lane = t, bits = n
            if (t < T) mask[((size_t)b * T + t) * 32 + nblk] = w;
        }
    } else if (bid < 2048) {
        __shared__ float tile[32][33];
        int idx = bid - 1024;
        int n0 = (idx & 63) * 32, m0 = (idx >> 6) * 32;
        int tx = threadIdx.x & 31, ty0 = threadIdx.x >> 5;
        #pragma unroll
        for (int i = 0; i < 4; ++i) {
            int ty = ty0 + 8 * i;
            tile[ty][tx] = W1[(size_t)(m0 + ty) * NIN + n0 + tx];
        }
        __syncthreads();
        #pragma unroll
        for (int i = 0; i < 4; ++i) {
            int ty = ty0 + 8 * i;
            W1T[(size_t)(n0 + ty) * NH + m0 + tx] = tile[tx][ty];
        }
    } else {
        int j = threadIdx.x;
        if (j < 192) {
            float v = 0.f;
            int i = j - 28;
            if (i >= 0 && i < 100) { float t = (float)i; v = (t * 0.1f) * expf(1.f - t * 0.1f); }
            srm28[j] = v;
        }
        for (int i = j; i < NH; i += 256) W1T[(size_t)2048 * NH + i] = 0.f;
    }
}

// ============ k_z1 (R4-exact): one wave per (b,t); LDS index list (pad x4 with
// zero-row 2048); 4 n / iter -> 8 dwordx4 in flight. Ascending-n summation.
__global__ void __launch_bounds__(64) k_z1(const uint64_t* __restrict__ mask,
                                           const float* __restrict__ W1T,
                                           float* __restrict__ z1) {
    __shared__ alignas(8) uint16_t lst[288];
    int row = blockIdx.x, lane = threadIdx.x;
    const uint64_t* mrow = mask + (size_t)row * 32;
    uint64_t w = (lane < 32) ? mrow[lane] : 0ull;
    int cnt = __popcll(w);
    int pre = cnt;
    #pragma unroll
    for (int off = 1; off < 64; off <<= 1) {
        int v = __shfl_up(pre, off);
        if (lane >= off) pre += v;
    }
    int total = __shfl(pre, 63);
    int excl = pre - cnt;
    while (w) {
        int bit = __builtin_ctzll(w);
        w &= w - 1;
        lst[excl++] = (uint16_t)((lane << 6) + bit);
    }
    int padded = (total + 3) & ~3;
    if (lane < padded - total) lst[total + lane] = 2048;   // zero row
    __syncthreads();

    const float4* W4 = (const float4*)W1T;
    float4 a0 = {0,0,0,0}, a1v = {0,0,0,0};
    int i0 = lane * 2, i1 = lane * 2 + 1;
    for (int k = 0; k < padded; k += 4) {
        ushort4 q = *(const ushort4*)(lst + k);
        const float4* p0 = W4 + (size_t)q.x * 128;
        const float4* p1 = W4 + (size_t)q.y * 128;
        const float4* p2 = W4 + (size_t)q.z * 128;
        const float4* p3 = W4 + (size_t)q.w * 128;
        float4 x0 = p0[i0], y0 = p0[i1];
        float4 x1 = p1[i0], y1 = p1[i1];
        float4 x2 = p2[i0], y2 = p2[i1];
        float4 x3 = p3[i0], y3 = p3[i1];
        a0.x += x0.x; a0.y += x0.y; a0.z += x0.z; a0.w += x0.w;
        a1v.x += y0.x; a1v.y += y0.y; a1v.z += y0.z; a1v.w += y0.w;
        a0.x += x1.x; a0.y += x1.y; a0.z += x1.z; a0.w += x1.w;
        a1v.x += y1.x; a1v.y += y1.y; a1v.z += y1.z; a1v.w += y1.w;
        a0.x += x2.x; a0.y += x2.y; a0.z += x2.z; a0.w += x2.w;
        a1v.x += y2.x; a1v.y += y2.y; a1v.z += y2.z; a1v.w += y2.w;
        a0.x += x3.x; a0.y += x3.y; a0.z += x3.z; a0.w += x3.w;
        a1v.x += y3.x; a1v.y += y3.y; a1v.z += y3.z; a1v.w += y3.w;
    }
    float4* zp = (float4*)(z1 + (size_t)row * NH);
    zp[i0] = a0; zp[i1] = a1v;
}

// ============ k_fir1: causal FIR K=100, M=512 (R4-exact)
__global__ void __launch_bounds__(64) k_fir1(const float* __restrict__ src,
                                             float* __restrict__ dst,
                                             const float* __restrict__ srm28) {
    __shared__ float tb[192];
    int b = blockIdx.x, half = blockIdx.y, tg = blockIdx.z;
    int lane = threadIdx.x;
    for (int i = lane; i < 192; i += 64) tb[i] = srm28[i];
    __syncthreads();
    int t0 = tg * 16;
    int m = half * 256 + lane * 4;
    const float* sp = src + (size_t)b * T * NH + m;

    float4 acc[16];
    #pragma unroll
    for (int r = 0; r < 16; ++r) acc[r] = make_float4(0.f, 0.f, 0.f, 0.f);
    float c[16];
    #pragma unroll
    for (int r = 0; r < 16; ++r) c[r] = tb[r + 127];

    for (int o = 0; o < 8; ++o) {
        #pragma unroll
        for (int j = 0; j < 16; ++j) {
            int dd = o * 16 + j;
            int tau = t0 - 99 + dd;
            float4 v = make_float4(0.f, 0.f, 0.f, 0.f);
            if (tau >= 0 && tau < T) v = *(const float4*)(sp + (size_t)tau * NH);
            #pragma unroll
            for (int r = 0; r < 16; ++r) {
                acc[r].x += c[r] * v.x; acc[r].y += c[r] * v.y;
                acc[r].z += c[r] * v.z; acc[r].w += c[r] * v.w;
            }
            #pragma unroll
            for (int r = 15; r > 0; --r) c[r] = c[r - 1];
            int ci = 126 - dd;
            c[0] = tb[ci < 0 ? 0 : ci];
        }
    }
    #pragma unroll
    for (int r = 0; r < 16; ++r) {
        int t = t0 + r;
        if (t < T) *(float4*)(dst + ((size_t)b * T + t) * NH + m) = acc[r];
    }
}

// ============ k_scanz2: fused layer-1 spike scan + z2 matmul.
// block = one b, 512 threads (thread = m). W2 in LDS. Per 16-t chunk:
// scan recurrence -> per-wave ballot -> mask words in LDS -> 160 threads
// gather-sum W2[o][m] over set bits (ascending m). s1 never hits global.
__global__ void __launch_bounds__(512) k_scanz2(const float* __restrict__ a1,
                                                const float* __restrict__ W2,
                                                float* __restrict__ z2) {
    __shared__ float w2s[NO * NH];        // 20 KB
    __shared__ uint64_t smask[16][8];
    constexpr int CT = 16;
    constexpr int NC = (T + CT - 1) / CT; // 22
    int b = blockIdx.x, tid = threadIdx.x;
    int wv = tid >> 6;
    for (int i = tid; i < NO * NH; i += 512) w2s[i] = W2[i];
    const float* up = a1 + (size_t)b * T * NH + tid;
    float A = 0.f, Bs = 0.f;
    float cur[CT], nxt[CT];
    #pragma unroll
    for (int j = 0; j < CT; ++j) cur[j] = up[(size_t)j * NH];
    __syncthreads();
    for (int c = 0; c < NC; ++c) {
        int t0 = c * CT;
        int nsteps = (T - t0 < CT) ? (T - t0) : CT;
        if (c + 1 < NC) {
            #pragma unroll
            for (int j = 0; j < CT; ++j) {
                int t = t0 + CT + j;
                nxt[j] = (t < T) ? up[(size_t)t * NH] : 0.f;
            }
        }
        #pragma unroll
        for (int j = 0; j < CT; ++j) {
            if (j < nsteps) {                       // nsteps uniform -> safe ballot
                float mem = cur[j] - CREF * Bs;
                float sp = (mem >= THETA) ? 1.0f : 0.0f;
                A = sp + BETA * A;
                Bs = BETA * (Bs + A);
                uint64_t mk = __ballot(sp != 0.0f);
                if ((tid & 63) == 0) smask[j][wv] = mk;
            }
        }
        __syncthreads();
        if (tid < nsteps * NO) {
            int j = tid / NO, o = tid - j * NO;
            const float* wrow = w2s + o * NH;
            float acc = 0.f;
            #pragma unroll
            for (int w8 = 0; w8 < 8; ++w8) {
                uint64_t mk = smask[j][w8];
                int base = w8 * 64;
                while (mk) {
                    int bit = __builtin_ctzll(mk);
                    mk &= mk - 1;
                    acc += wrow[base + bit];
                }
            }
            z2[((size_t)b * T + t0 + j) * NO + o] = acc;
        }
        __syncthreads();
        #pragma unroll
        for (int j = 0; j < CT; ++j) cur[j] = nxt[j];
    }
}

// ============ k_fir2scan (R4-exact)
__global__ void __launch_bounds__(256) k_fir2scan(const float* __restrict__ z2,
                                                  const float* __restrict__ srm28,
                                                  float* __restrict__ out) {
    __shared__ float tb[192];
    __shared__ float zb[350 * 11 + 16];
    __shared__ float ab[352 * 10];
    int b = blockIdx.x, tid = threadIdx.x;
    if (tid < 192) tb[tid] = srm28[tid];
    const float* zp = z2 + (size_t)b * T * NO;
    for (int i = tid; i < T * NO; i += 256) {
        int t = i / NO, o = i - t * NO;
        zb[t * 11 + o] = zp[i];
    }
    __syncthreads();
    if (tid < 220) {
        int tt = tid / 10, o = tid - tt * 10;
        int t0 = tt * 16;
        float acc[16];
        #pragma unroll
        for (int r = 0; r < 16; ++r) acc[r] = 0.f;
        float c[16];
        #pragma unroll
        for (int r = 0; r < 16; ++r) c[r] = tb[r + 127];
        for (int oo = 0; oo < 8; ++oo) {
            #pragma unroll
            for (int j = 0; j < 16; ++j) {
                int dd = oo * 16 + j;
                int tau = t0 - 99 + dd;
                float v = (tau >= 0 && tau < T) ? zb[tau * 11 + o] : 0.f;
                #pragma unroll
                for (int r = 0; r < 16; ++r) acc[r] += c[r] * v;
                #pragma unroll
                for (int r = 15; r > 0; --r) c[r] = c[r - 1];
                int ci = 126 - dd;
                c[0] = tb[ci < 0 ? 0 : ci];
            }
        }
        #pragma unroll
        for (int r = 0; r < 16; ++r) {
            int t = t0 + r;
            if (t < T) ab[t * 10 + o] = acc[r];
        }
    }
    __syncthreads();
    if (tid < NO) {
        int o = tid;
        float A = 0.f, Bs = 0.f;
        float* op = out + ((size_t)b * NO + o) * T;
        for (int t = 0; t < T; ++t) {
            float mem = ab[t * 10 + o] - CREF * Bs;
            float sp = (mem >= THETA) ? 1.0f : 0.0f;
            A = sp + BETA * A;
            Bs = BETA * (Bs + A);
            op[t] = sp;
        }
    }
}

extern "C" void kernel_launch(void* const* d_in, const int* in_sizes, int n_in,
                              void* d_out, int out_size, void* d_ws, size_t ws_size,
                              hipStream_t stream) {
    const float* x  = (const float*)d_in[0];
    const float* W1 = (const float*)d_in[1];
    const float* W2 = (const float*)d_in[2];
    char* ws = (char*)d_ws;
    float*    W1T  = (float*)(ws + OFF_W1T);
    uint64_t* mask = (uint64_t*)(ws + OFF_MASK);
    float*    srm  = (float*)(ws + OFF_SRM);
    float*    z1   = (float*)(ws + OFF_Z1);
    float*    a1   = (float*)(ws + OFF_A1);
    float*    z2   = (float*)(ws + OFF_Z2);   // reuse z1 region (dead after fir1)
    float*    out  = (float*)d_out;

    hipLaunchKernelGGL(k_prep,     dim3(2049),     dim3(256), 0, stream, x, W1, W1T, mask, srm);
    hipLaunchKernelGGL(k_z1,       dim3(BT),       dim3(64),  0, stream, mask, W1T, z1);
    hipLaunchKernelGGL(k_fir1,     dim3(B, 2, 22), dim3(64),  0, stream, z1, a1, srm);
    hipLaunchKernelGGL(k_scanz2,   dim3(B),        dim3(512), 0, stream, a1, W2, z2);
    hipLaunchKernelGGL(k_fir2scan, dim3(B),        dim3(256), 0, stream, z2, srm, out);
}